// Round 14
// baseline (2132.074 us; speedup 1.0000x reference)
//
#include <hip/hip_runtime.h>
#include <hip/hip_bf16.h>
#include <math.h>

#define NN 50000
#define TT 4
#define RR 3
#define EE 500000
#define RANGE 6400
#define NRANGE 8

typedef __attribute__((ext_vector_type(8))) short bf16x8;
typedef __attribute__((ext_vector_type(4))) float f32x4;

__device__ inline unsigned short f2b(float f)
{
    union { __hip_bfloat16 h; unsigned short u; } cv;
    cv.h = __float2bfloat16(f);
    return cv.u;
}
__device__ inline float b2f(unsigned short u)
{
    union { unsigned int u; float f; } cv;
    cv.u = ((unsigned int)u) << 16;
    return cv.f;
}
__device__ inline bf16x8 pack8(float4 a, float4 b)
{
    bf16x8 r;
    r[0] = (short)f2b(a.x); r[1] = (short)f2b(a.y); r[2] = (short)f2b(a.z); r[3] = (short)f2b(a.w);
    r[4] = (short)f2b(b.x); r[5] = (short)f2b(b.y); r[6] = (short)f2b(b.z); r[7] = (short)f2b(b.w);
    return r;
}

// ---------------- diagnostic fill ----------------

__global__ __launch_bounds__(256)
void diag_kernel(float* __restrict__ out, float v)
{
    int i = blockIdx.x * 256 + threadIdx.x;
    if (i < NN) out[i] = v;
}

// ---------------- weight swizzle: (S,128,C) fp32 -> MFMA B-frag bf16 ----------

__global__ __launch_bounds__(256)
void wswz_kernel(const float* __restrict__ W, unsigned short* __restrict__ dst, int C, int S)
{
    int idx = blockIdx.x * 256 + threadIdx.x;
    int per = 128 * C;
    if (idx >= S * per) return;
    int s = idx / per, rem = idx - s * per;
    int j = rem & 7;
    int lane = (rem >> 3) & 63;
    int blk = rem >> 9;
    int ncg = C >> 4;
    int kc = blk / ncg, cg = blk - kc * ncg;
    int k = kc * 32 + (lane >> 4) * 8 + j;
    int c = cg * 16 + (lane & 15);
    dst[idx] = f2b(W[(size_t)s * 128 * C + (size_t)k * C + c]);
}

// ---------------- CSR count via per-(graph,range) LDS histogram --------------

__global__ __launch_bounds__(1024)
void count_hist(const int* __restrict__ dst, int* __restrict__ cnt)
{
    __shared__ int hist[RANGE];
    const int g = blockIdx.y;
    const int r0 = blockIdx.x * RANGE;
    for (int i = threadIdx.x; i < RANGE; i += 1024) hist[i] = 0;
    __syncthreads();
    const int4* d4 = (const int4*)(dst + (size_t)g * EE);
    for (int i = threadIdx.x; i < EE / 4; i += 1024) {
        int4 v = d4[i];
        int a0 = v.x - r0; if ((unsigned)a0 < (unsigned)RANGE) atomicAdd(&hist[a0], 1);
        int a1 = v.y - r0; if ((unsigned)a1 < (unsigned)RANGE) atomicAdd(&hist[a1], 1);
        int a2 = v.z - r0; if ((unsigned)a2 < (unsigned)RANGE) atomicAdd(&hist[a2], 1);
        int a3 = v.w - r0; if ((unsigned)a3 < (unsigned)RANGE) atomicAdd(&hist[a3], 1);
    }
    __syncthreads();
    int* c = cnt + (size_t)g * NN;
    for (int i = threadIdx.x; i < RANGE; i += 1024) {
        int n = r0 + i;
        if (n < NN) c[n] = hist[i];
    }
}

__global__ __launch_bounds__(1024)
void scan_kernel(int* __restrict__ cnt, int* __restrict__ rows)
{
    int g = blockIdx.x;
    int tid = threadIdx.x;
    const int CH = (NN + 1023) / 1024;
    int s0 = tid * CH;
    int s1 = s0 + CH; if (s1 > NN) s1 = NN;
    int* c = cnt + (size_t)g * NN;
    int* ro = rows + (size_t)g * (NN + 1);
    int sum = 0;
    for (int i = s0; i < s1; ++i) sum += c[i];
    __shared__ int sd[1024];
    sd[tid] = sum;
    __syncthreads();
    for (int off = 1; off < 1024; off <<= 1) {
        int v = 0;
        if (tid >= off) v = sd[tid - off];
        __syncthreads();
        sd[tid] += v;
        __syncthreads();
    }
    int total = sd[1023];
    int prefix = (tid == 0) ? 0 : sd[tid - 1];
    for (int i = s0; i < s1; ++i) {
        int cv = c[i];
        ro[i] = prefix;
        c[i] = prefix;
        prefix += cv;
    }
    if (tid == 0) ro[NN] = total;
}

// ---------------- CSR fill via per-(graph,range) LDS cursors -----------------
// blockIdx.x = node range, blockIdx.y = graph (all T*R at once). Cursor starts
// come from the scanned CURS; LDS atomics only, zero global atomics.

__global__ __launch_bounds__(1024)
void fill_hist(const int* __restrict__ src, const int* __restrict__ dst,
               const float* __restrict__ ew, const int* __restrict__ cur_start,
               int2* __restrict__ srcw)
{
    __shared__ int cur[RANGE];
    const int g = blockIdx.y;
    const int r0 = blockIdx.x * RANGE;
    const int* cs = cur_start + (size_t)g * NN;
    for (int i = threadIdx.x; i < RANGE; i += 1024) {
        int n = r0 + i;
        cur[i] = (n < NN) ? cs[n] : 0;
    }
    __syncthreads();
    const size_t base = (size_t)g * EE;
    int2* sw = srcw + base;
    for (int i = threadIdx.x; i < EE; i += 1024) {
        int d = dst[base + i];
        int a = d - r0;
        if ((unsigned)a < (unsigned)RANGE) {
            int pos = atomicAdd(&cur[a], 1);
            int2 p;
            p.x = src[base + i];
            p.y = __float_as_int(ew[base + i]);
            sw[pos] = p;
        }
    }
}

// ---------------- conv gather-aggregate, predicated 16-batch -----------------

__global__ __launch_bounds__(256)
void agg16_kernel(const unsigned short* __restrict__ x16,  // (N,128) bf16
                  const int2* __restrict__ srcw,           // (R,E)
                  const int* __restrict__ rows,            // (R,N+1)
                  unsigned short* __restrict__ agg16)      // (R,N,128) bf16
{
    int wid = (blockIdx.x * 256 + threadIdx.x) >> 6;
    int lane = threadIdx.x & 63;
    if (wid >= RR * NN) return;
    int r = wid / NN;
    int n = wid - r * NN;
    const int* rs = rows + (size_t)r * (NN + 1);
    int e0 = rs[n], e1 = rs[n + 1];
    const int2* sw = srcw + (size_t)r * EE;
    const int co = lane * 2;
    float ax = 0.f, ay = 0.f;
    for (int e = e0; e < e1; e += 16) {
        int2 p[16];
        unsigned int v[16];
#pragma unroll
        for (int i = 0; i < 16; ++i) {
            int idx = (e + i < e1) ? e + i : e1 - 1;
            p[i] = sw[idx];
        }
#pragma unroll
        for (int i = 0; i < 16; ++i)
            v[i] = *(const unsigned int*)(x16 + (size_t)p[i].x * 128 + co);
#pragma unroll
        for (int i = 0; i < 16; ++i) {
            float w = (e + i < e1) ? __int_as_float(p[i].y) : 0.f;
            ax += w * b2f((unsigned short)(v[i] & 0xffffu));
            ay += w * b2f((unsigned short)(v[i] >> 16));
        }
    }
    float inv = 1.0f / fmaxf((float)(e1 - e0), 1.0f);
    unsigned int o = (unsigned int)f2b(ax * inv) | ((unsigned int)f2b(ay * inv) << 16);
    *(unsigned int*)(agg16 + ((size_t)r * NN + n) * 128 + co) = o;
}

// ---------------- MFMA matmul: out = act(in @ W + b), K=128, 128 cols --------

__global__ __launch_bounds__(256)
void mmb(const void* in, int in_bf16, long in_zs, int ldin,
         const unsigned short* __restrict__ Ws, long w_zs,
         const float* __restrict__ bias, long b_zs,
         float* out, long out_zs, int ldout,
         unsigned short* out16, long out16_zs,
         int rows, int act)
{
    const int tid = threadIdx.x;
    const int wv = tid >> 6, l = tid & 63;
    const int z = blockIdx.z;
    const int r0 = blockIdx.x * 64 + wv * 16;
    const int lk = (l >> 4) * 8;
    int rowA = r0 + (l & 15);
    int rowc = rowA < rows ? rowA : rows - 1;

    bf16x8 a[4];
    if (in_bf16) {
        const unsigned short* inb = (const unsigned short*)in + (size_t)z * in_zs
                                    + (size_t)rowc * ldin + lk;
#pragma unroll
        for (int kc = 0; kc < 4; ++kc) {
            uint4 u = *(const uint4*)(inb + kc * 32);
            a[kc] = *(bf16x8*)&u;
        }
    } else {
        const float* inf = (const float*)in + (size_t)z * in_zs
                           + (size_t)rowc * ldin + lk;
#pragma unroll
        for (int kc = 0; kc < 4; ++kc) {
            float4 u0 = *(const float4*)(inf + kc * 32);
            float4 u1 = *(const float4*)(inf + kc * 32 + 4);
            a[kc] = pack8(u0, u1);
        }
    }

    const unsigned short* Wz = Ws + (size_t)z * w_zs;
    const float* bz = bias + (size_t)z * b_zs;
    float* oz = out ? out + (size_t)z * out_zs : (float*)0;
    unsigned short* o16z = out16 ? out16 + (size_t)z * out16_zs : (unsigned short*)0;
    const int colbase = l & 15;
    const int rbase = r0 + (l >> 4) * 4;

#pragma unroll
    for (int cg = 0; cg < 8; ++cg) {
        f32x4 acc = {0.f, 0.f, 0.f, 0.f};
#pragma unroll
        for (int kc = 0; kc < 4; ++kc) {
            uint4 bu = *(const uint4*)(Wz + ((size_t)(kc * 8 + cg) * 64 + l) * 8);
            acc = __builtin_amdgcn_mfma_f32_16x16x32_bf16(a[kc], *(bf16x8*)&bu, acc, 0, 0, 0);
        }
        int col = cg * 16 + colbase;
        float bvv = bz[col];
#pragma unroll
        for (int j = 0; j < 4; ++j) {
            int gr = rbase + j;
            if (gr >= rows) continue;
            float v = acc[j] + bvv;
            if (act) v = fmaxf(v, 0.f);
            if (oz) oz[(size_t)gr * ldout + col] = v;
            if (o16z) o16z[(size_t)gr * 128 + col] = f2b(v);
        }
    }
}

// ---------------- fused 4-timestep MFMA GRU: HS[t] <- outs_t (in-place) ------
// t-loop MUST stay rolled (#pragma unroll 1): full unroll quadruples live
// ranges -> 256 VGPR + scratch spill (round-12 regression, FETCH 719 MB).

__global__ __launch_bounds__(256)
void grub4(float* HS,                         // (T,N,128) fp32, in/out
           const unsigned short* __restrict__ Wis, const float* __restrict__ bi,
           const unsigned short* __restrict__ Whs, const float* __restrict__ bh)
{
    __shared__ __align__(16) unsigned short hbuf[4][16 * 136];
    const int tid = threadIdx.x;
    const int wv = tid >> 6, l = tid & 63;
    const int r0 = blockIdx.x * 64 + wv * 16;
    const int lo = l & 15, hi = l >> 4;
    const int lk = hi * 8;
    const int rowc = (r0 + lo) < NN ? (r0 + lo) : NN - 1;
    const int rbase = r0 + hi * 4;
    unsigned short* hb = hbuf[wv];

    for (int i = l; i < 16 * 136; i += 64) hb[i] = 0;

    float hold[8][4];
#pragma unroll
    for (int cg = 0; cg < 8; ++cg)
#pragma unroll
        for (int j = 0; j < 4; ++j) hold[cg][j] = 0.f;

#pragma unroll 1
    for (int t = 0; t < TT; ++t) {
        float* xt = HS + (size_t)t * NN * 128;
        bf16x8 ax[4], hx[4];
        const float* bx = xt + (size_t)rowc * 128 + lk;
#pragma unroll
        for (int kc = 0; kc < 4; ++kc) {
            ax[kc] = pack8(*(const float4*)(bx + kc * 32), *(const float4*)(bx + kc * 32 + 4));
            uint4 hu = *(const uint4*)(hb + lo * 136 + kc * 32 + lk);
            hx[kc] = *(bf16x8*)&hu;
        }

#pragma unroll 1
        for (int cg = 0; cg < 8; ++cg) {
            f32x4 air = {0.f,0.f,0.f,0.f}, ahr = {0.f,0.f,0.f,0.f};
            f32x4 aiz = {0.f,0.f,0.f,0.f}, ahz = {0.f,0.f,0.f,0.f};
            f32x4 ain = {0.f,0.f,0.f,0.f}, ahn = {0.f,0.f,0.f,0.f};
#pragma unroll
            for (int kc = 0; kc < 4; ++kc) {
                uint4 br = *(const uint4*)(Wis + ((size_t)(kc * 24 + 0 + cg) * 64 + l) * 8);
                uint4 hr = *(const uint4*)(Whs + ((size_t)(kc * 24 + 0 + cg) * 64 + l) * 8);
                uint4 bz = *(const uint4*)(Wis + ((size_t)(kc * 24 + 8 + cg) * 64 + l) * 8);
                uint4 hz = *(const uint4*)(Whs + ((size_t)(kc * 24 + 8 + cg) * 64 + l) * 8);
                uint4 bn = *(const uint4*)(Wis + ((size_t)(kc * 24 + 16 + cg) * 64 + l) * 8);
                uint4 hn = *(const uint4*)(Whs + ((size_t)(kc * 24 + 16 + cg) * 64 + l) * 8);
                air = __builtin_amdgcn_mfma_f32_16x16x32_bf16(ax[kc], *(bf16x8*)&br, air, 0, 0, 0);
                ahr = __builtin_amdgcn_mfma_f32_16x16x32_bf16(hx[kc], *(bf16x8*)&hr, ahr, 0, 0, 0);
                aiz = __builtin_amdgcn_mfma_f32_16x16x32_bf16(ax[kc], *(bf16x8*)&bz, aiz, 0, 0, 0);
                ahz = __builtin_amdgcn_mfma_f32_16x16x32_bf16(hx[kc], *(bf16x8*)&hz, ahz, 0, 0, 0);
                ain = __builtin_amdgcn_mfma_f32_16x16x32_bf16(ax[kc], *(bf16x8*)&bn, ain, 0, 0, 0);
                ahn = __builtin_amdgcn_mfma_f32_16x16x32_bf16(hx[kc], *(bf16x8*)&hn, ahn, 0, 0, 0);
            }
            int col = cg * 16 + lo;
            float bir = bi[col],       bhr = bh[col];
            float biz = bi[128 + col], bhz = bh[128 + col];
            float bin = bi[256 + col], bhn = bh[256 + col];
#pragma unroll
            for (int j = 0; j < 4; ++j) {
                float r_ = 1.f / (1.f + __expf(-(air[j] + bir + ahr[j] + bhr)));
                float z_ = 1.f / (1.f + __expf(-(aiz[j] + biz + ahz[j] + bhz)));
                float n_ = tanhf(ain[j] + bin + r_ * (ahn[j] + bhn));
                float o = (1.f - z_) * n_ + z_ * hold[cg][j];
                hold[cg][j] = o;
                int gr = rbase + j;
                if (gr < NN) xt[(size_t)gr * 128 + col] = o;   // outs_t (in-place)
                hb[(hi * 4 + j) * 136 + col] = f2b(o);          // h for next t (A-side)
            }
        }
    }
}

// ---------------- MFMA classifier: out = relu(Z @ cW1 + cb1) . cW2 + cb2 -----

__global__ __launch_bounds__(256)
void cls_mfma(const float* __restrict__ in,             // (N,384) fp32
              const unsigned short* __restrict__ Ws,    // swizzled cW1 (3 slices)
              const float* __restrict__ b1_,            // (128)
              const float* __restrict__ w2,             // (128)
              const float* __restrict__ b2_,            // (1)
              float* __restrict__ outv, int rows)
{
    const int tid = threadIdx.x;
    const int wv = tid >> 6, l = tid & 63;
    const int r0 = blockIdx.x * 64 + wv * 16;
    const int lk = (l >> 4) * 8;
    int rowA = r0 + (l & 15);
    int rowc = rowA < rows ? rowA : rows - 1;

    bf16x8 a[12];
    {
        const float* inf = in + (size_t)rowc * 384 + lk;
#pragma unroll
        for (int kc = 0; kc < 12; ++kc) {
            float4 u0 = *(const float4*)(inf + kc * 32);
            float4 u1 = *(const float4*)(inf + kc * 32 + 4);
            a[kc] = pack8(u0, u1);
        }
    }
    const int colbase = l & 15;
    const int rbase = r0 + (l >> 4) * 4;
    float part[4] = {0.f, 0.f, 0.f, 0.f};

#pragma unroll
    for (int cg = 0; cg < 8; ++cg) {
        f32x4 acc = {0.f, 0.f, 0.f, 0.f};
#pragma unroll
        for (int kc = 0; kc < 12; ++kc) {
            uint4 bu = *(const uint4*)(Ws + ((size_t)(kc * 8 + cg) * 64 + l) * 8);
            acc = __builtin_amdgcn_mfma_f32_16x16x32_bf16(a[kc], *(bf16x8*)&bu, acc, 0, 0, 0);
        }
        int col = cg * 16 + colbase;
        float b1v = b1_[col];
        float w2v = w2[col];
#pragma unroll
        for (int j = 0; j < 4; ++j)
            part[j] += fmaxf(acc[j] + b1v, 0.f) * w2v;
    }
    const float cb2v = b2_[0];
#pragma unroll
    for (int j = 0; j < 4; ++j) {
#pragma unroll
        for (int m = 1; m < 16; m <<= 1) part[j] += __shfl_xor(part[j], m);
        int gr = rbase + j;
        if ((l & 15) == 0 && gr < rows) outv[gr] = part[j] + cb2v;
    }
}

// ---------------- fused rel-attn + relu + residual + LayerNorm ----------------

__device__ inline float wred(float v)
{
#pragma unroll
    for (int m = 32; m; m >>= 1) v += __shfl_xor(v, m);
    return v;
}

__global__ __launch_bounds__(256)
void attnln_kernel(const unsigned short* __restrict__ agg16, // (R,N,128) bf16
                   const unsigned short* hin16,              // (N,128) bf16, may alias hout16
                   const float* __restrict__ q,
                   const float* __restrict__ g,
                   const float* __restrict__ b,
                   float* hout,                              // optional fp32
                   unsigned short* hout16)                   // optional bf16
{
    int wid = (blockIdx.x * 256 + threadIdx.x) >> 6;
    int lane = threadIdx.x & 63;
    if (wid >= NN) return;
    int n = wid;
    float2 qv = *(const float2*)(q + lane * 2);
    float sx[3], sy[3], sc[3];
#pragma unroll
    for (int r = 0; r < 3; ++r) {
        unsigned int v = *(const unsigned int*)(agg16 + ((size_t)r * NN + n) * 128 + lane * 2);
        sx[r] = b2f((unsigned short)(v & 0xffffu));
        sy[r] = b2f((unsigned short)(v >> 16));
        sc[r] = wred(tanhf(sx[r]) * qv.x + tanhf(sy[r]) * qv.y);
    }
    float mx = fmaxf(sc[0], fmaxf(sc[1], sc[2]));
    float e0 = __expf(sc[0] - mx), e1 = __expf(sc[1] - mx), e2 = __expf(sc[2] - mx);
    float isum = 1.f / (e0 + e1 + e2);
    float axv = (e0 * sx[0] + e1 * sx[1] + e2 * sx[2]) * isum;
    float ayv = (e0 * sy[0] + e1 * sy[1] + e2 * sy[2]) * isum;
    unsigned int hv = *(const unsigned int*)(hin16 + (size_t)n * 128 + lane * 2);
    float ux = b2f((unsigned short)(hv & 0xffffu)) + fmaxf(axv, 0.f);
    float uy = b2f((unsigned short)(hv >> 16)) + fmaxf(ayv, 0.f);
    float mean = wred(ux + uy) * (1.f / 128.f);
    float dx = ux - mean, dy = uy - mean;
    float var = wred(dx * dx + dy * dy) * (1.f / 128.f);
    float rstd = rsqrtf(var + 1e-5f);
    float2 gv = *(const float2*)(g + lane * 2);
    float2 bv = *(const float2*)(b + lane * 2);
    float ox = dx * rstd * gv.x + bv.x;
    float oy = dy * rstd * gv.y + bv.y;
    if (hout) {
        float2 o; o.x = ox; o.y = oy;
        *(float2*)(hout + (size_t)n * 128 + lane * 2) = o;
    }
    if (hout16) {
        unsigned int p = (unsigned int)f2b(ox) | ((unsigned int)f2b(oy) << 16);
        *(unsigned int*)(hout16 + (size_t)n * 128 + lane * 2) = p;
    }
}

// ---------------- temporal attention (also emits `last`) ----------------

__global__ __launch_bounds__(256)
void temporal_kernel(const float* __restrict__ outs, // (T,N,128)
                     const float* __restrict__ tq,
                     float* __restrict__ zbuf)       // (N,384)
{
    int wid = (blockIdx.x * 256 + threadIdx.x) >> 6;
    int lane = threadIdx.x & 63;
    if (wid >= NN) return;
    int n = wid;
    float2 qv = *(const float2*)(tq + lane * 2);
    float2 o[4];
    float sc[4];
#pragma unroll
    for (int t = 0; t < 4; ++t) {
        o[t] = *(const float2*)(outs + ((size_t)t * NN + n) * 128 + lane * 2);
        sc[t] = wred(tanhf(o[t].x) * qv.x + tanhf(o[t].y) * qv.y);
    }
    float mx = fmaxf(fmaxf(sc[0], sc[1]), fmaxf(sc[2], sc[3]));
    float e[4];
    float sum = 0.f;
#pragma unroll
    for (int t = 0; t < 4; ++t) { e[t] = __expf(sc[t] - mx); sum += e[t]; }
    float isum = 1.f / sum;
    float axv = 0.f, ayv = 0.f;
#pragma unroll
    for (int t = 0; t < 4; ++t) { axv += e[t] * o[t].x; ayv += e[t] * o[t].y; }
    axv *= isum; ayv *= isum;
    float* zr = zbuf + (size_t)n * 384;
    *(float2*)(zr + lane * 2) = o[3];
    float2 at; at.x = axv; at.y = ayv;
    *(float2*)(zr + 128 + lane * 2) = at;
}

// ---------------- launch ----------------

extern "C" void kernel_launch(void* const* d_in, const int* in_sizes, int n_in,
                              void* d_out, int out_size, void* d_ws, size_t ws_size,
                              hipStream_t stream)
{
    const float* feat = (const float*)d_in[0];
    const int* srcp   = (const int*)d_in[1];
    const int* dstp   = (const int*)d_in[2];
    const float* ewp  = (const float*)d_in[3];
    const float* W_in = (const float*)d_in[4];
    const float* b_in = (const float*)d_in[5];
    const float* W1   = (const float*)d_in[6];
    const float* b1   = (const float*)d_in[7];
    const float* W2   = (const float*)d_in[8];
    const float* b2   = (const float*)d_in[9];
    const float* q1   = (const float*)d_in[10];
    const float* q2   = (const float*)d_in[11];
    const float* ln1g = (const float*)d_in[12];
    const float* ln1b = (const float*)d_in[13];
    const float* ln2g = (const float*)d_in[14];
    const float* ln2b = (const float*)d_in[15];
    const float* gWih = (const float*)d_in[16];
    const float* gbih = (const float*)d_in[17];
    const float* gWhh = (const float*)d_in[18];
    const float* gbhh = (const float*)d_in[19];
    const float* tq   = (const float*)d_in[20];
    const float* tW1  = (const float*)d_in[21];
    const float* tb1  = (const float*)d_in[22];
    const float* tW2  = (const float*)d_in[23];
    const float* tb2  = (const float*)d_in[24];
    const float* cW1  = (const float*)d_in[25];
    const float* cb1  = (const float*)d_in[26];
    const float* cW2  = (const float*)d_in[27];
    const float* cb2  = (const float*)d_in[28];
    float* outv = (float*)d_out;
    (void)in_sizes; (void)n_in; (void)out_size;

    // ---- ws layout (bytes), peak ~207.0 MB (<=218 proven) ----
    // SRCW now holds ALL 12 graphs (fill hoisted out of the t-loop).
    // phase C: ZB (76.8M) overlays AGG16/H16/SRCW[0..25.6M]; TAB16 at
    // POOL+76.8M sits inside SRCW's dead region. ROWS/CURS/WSZ untouched.
    const size_t o_HS    = 0;                          // (T,N,128) fp32 = 102,400,000
    const size_t o_POOL  = 102400000;
    const size_t o_AGG16 = o_POOL;                     // (R,N,128) bf16 = 38,400,000
    const size_t o_H16   = o_POOL + 38400000;          // (N,128) bf16 = 12,800,000
    const size_t o_SRCW  = o_POOL + 51200000;          // (12,E) int2 = 48,000,000
    const size_t o_ROWS  = o_POOL + 99200000;          // (12,N+1) int -> pad
    const size_t o_CURS  = o_POOL + 101600128;         // (12,N) int
    const size_t o_ZB    = o_POOL;                     // phase C: (N,384) fp32
    const size_t o_TAB   = o_POOL + 76800000;          // phase C: (N,128) bf16
    const size_t o_WSZ   = o_POOL + 104000128;         // swizzled bf16 weights
    const size_t NEED    = o_WSZ + 589824;

    if (ws_size < NEED) {
        diag_kernel<<<dim3((NN + 255) / 256), dim3(256), 0, stream>>>(outv, (float)(ws_size >> 20));
        return;
    }

    char* wsb = (char*)d_ws;
    float* HS             = (float*)(wsb + o_HS);
    unsigned short* AGG16 = (unsigned short*)(wsb + o_AGG16);
    unsigned short* H16   = (unsigned short*)(wsb + o_H16);
    int2*  SRCW           = (int2*)(wsb + o_SRCW);
    int*   ROWS           = (int*)(wsb + o_ROWS);
    int*   CURS           = (int*)(wsb + o_CURS);
    float* ZB             = (float*)(wsb + o_ZB);
    unsigned short* TAB16 = (unsigned short*)(wsb + o_TAB);
    unsigned short* WSZ   = (unsigned short*)(wsb + o_WSZ);

    unsigned short* Wins  = WSZ;            // 16384
    unsigned short* W1s   = WSZ + 16384;    // 49152
    unsigned short* W2s   = WSZ + 65536;    // 49152
    unsigned short* gWihs = WSZ + 114688;   // 49152
    unsigned short* gWhhs = WSZ + 163840;   // 49152
    unsigned short* tW1s  = WSZ + 212992;   // 16384
    unsigned short* tW2s  = WSZ + 229376;   // 16384
    unsigned short* cW1s  = WSZ + 245760;   // 49152

    const dim3 blk(256);
    const int G64 = (NN + 63) / 64;

    // ---------- weight swizzle ----------
    wswz_kernel<<<dim3((1 * 16384 + 255) / 256), blk, 0, stream>>>(W_in, Wins, 128, 1);
    wswz_kernel<<<dim3((3 * 16384 + 255) / 256), blk, 0, stream>>>(W1,   W1s,  128, 3);
    wswz_kernel<<<dim3((3 * 16384 + 255) / 256), blk, 0, stream>>>(W2,   W2s,  128, 3);
    wswz_kernel<<<dim3((1 * 49152 + 255) / 256), blk, 0, stream>>>(gWih, gWihs, 384, 1);
    wswz_kernel<<<dim3((1 * 49152 + 255) / 256), blk, 0, stream>>>(gWhh, gWhhs, 384, 1);
    wswz_kernel<<<dim3((1 * 16384 + 255) / 256), blk, 0, stream>>>(tW1,  tW1s, 128, 1);
    wswz_kernel<<<dim3((1 * 16384 + 255) / 256), blk, 0, stream>>>(tW2,  tW2s, 128, 1);
    wswz_kernel<<<dim3((3 * 16384 + 255) / 256), blk, 0, stream>>>(cW1,  cW1s, 128, 3);

    // ---------- CSR: count (LDS hist) + scan + fill (LDS cursors), all 12 graphs ----------
    count_hist<<<dim3(NRANGE, TT * RR), dim3(1024), 0, stream>>>(dstp, CURS);
    scan_kernel<<<dim3(TT * RR), dim3(1024), 0, stream>>>(CURS, ROWS);
    fill_hist<<<dim3(NRANGE, TT * RR), dim3(1024), 0, stream>>>(srcp, dstp, ewp, CURS, SRCW);

    // ---------- phase A: spatial layers, t-outer ----------
    for (int t = 0; t < TT; ++t) {
        // h0 = relu(feat[t] @ W_in + b_in) -> H16 (bf16 only)
        mmb<<<dim3(G64, 1, 1), blk, 0, stream>>>(
            (const void*)(feat + (size_t)t * NN * 128), 0, 0, 128,
            Wins, 0, b_in, 0, (float*)0, 0, 0, H16, 0, NN, 1);

        for (int layer = 0; layer < 2; ++layer) {
            const unsigned short* Wls = layer ? W2s : W1s;
            const float* bl = layer ? b2 : b1;
            const float* ql = layer ? q2 : q1;
            const float* lg = layer ? ln2g : ln1g;
            const float* lb = layer ? ln2b : ln1b;
            float* hout = layer ? (HS + (size_t)t * NN * 128) : (float*)0;
            unsigned short* hout16 = layer ? (unsigned short*)0 : H16;

            agg16_kernel<<<dim3((RR * NN) / 4), blk, 0, stream>>>(
                H16, SRCW + (size_t)t * RR * EE, ROWS + (size_t)t * RR * (NN + 1), AGG16);
            mmb<<<dim3(G64, 1, RR), blk, 0, stream>>>(
                (const void*)AGG16, 1, (long)NN * 128, 128,
                Wls, 16384, bl, 128, (float*)0, 0, 0, AGG16, (long)NN * 128, NN, 0);
            attnln_kernel<<<dim3(NN / 4), blk, 0, stream>>>(
                AGG16, H16, ql, lg, lb, hout, hout16);
        }
    }

    // ---------- phase B: fully-fused 4-step GRU (in-place on HS) ----------
    grub4<<<dim3(G64), blk, 0, stream>>>(HS, gWihs, gbih, gWhhs, gbhh);

    // ---------- phase C: temporal attn + tab + classifier ----------
    temporal_kernel<<<dim3(NN / 4), blk, 0, stream>>>(HS, tq, ZB);

    mmb<<<dim3(G64, 1, 1), blk, 0, stream>>>(
        (const void*)(feat + (size_t)3 * NN * 128), 0, 0, 128,
        tW1s, 0, tb1, 0, (float*)0, 0, 0, TAB16, 0, NN, 1);
    mmb<<<dim3(G64, 1, 1), blk, 0, stream>>>(
        (const void*)TAB16, 1, 0, 128,
        tW2s, 0, tb2, 0, ZB + 256, 0, 384, (unsigned short*)0, 0, NN, 1);

    cls_mfma<<<dim3(G64), blk, 0, stream>>>(ZB, cW1s, cb1, cW2, cb2, outv, NN);
}

// Round 15
// 1980.510 us; speedup vs baseline: 1.0765x; 1.0765x over previous
//
#include <hip/hip_runtime.h>
#include <hip/hip_bf16.h>
#include <math.h>

#define NN 50000
#define TT 4
#define RR 3
#define EE 500000
#define RANGE 6400
#define NRANGE 8

typedef __attribute__((ext_vector_type(8))) short bf16x8;
typedef __attribute__((ext_vector_type(4))) float f32x4;

__device__ inline unsigned short f2b(float f)
{
    union { __hip_bfloat16 h; unsigned short u; } cv;
    cv.h = __float2bfloat16(f);
    return cv.u;
}
__device__ inline float b2f(unsigned short u)
{
    union { unsigned int u; float f; } cv;
    cv.u = ((unsigned int)u) << 16;
    return cv.f;
}
__device__ inline bf16x8 pack8(float4 a, float4 b)
{
    bf16x8 r;
    r[0] = (short)f2b(a.x); r[1] = (short)f2b(a.y); r[2] = (short)f2b(a.z); r[3] = (short)f2b(a.w);
    r[4] = (short)f2b(b.x); r[5] = (short)f2b(b.y); r[6] = (short)f2b(b.z); r[7] = (short)f2b(b.w);
    return r;
}

// ---------------- diagnostic fill ----------------

__global__ __launch_bounds__(256)
void diag_kernel(float* __restrict__ out, float v)
{
    int i = blockIdx.x * 256 + threadIdx.x;
    if (i < NN) out[i] = v;
}

// ---------------- weight swizzle: (S,128,C) fp32 -> MFMA B-frag bf16 ----------

__global__ __launch_bounds__(256)
void wswz_kernel(const float* __restrict__ W, unsigned short* __restrict__ dst, int C, int S)
{
    int idx = blockIdx.x * 256 + threadIdx.x;
    int per = 128 * C;
    if (idx >= S * per) return;
    int s = idx / per, rem = idx - s * per;
    int j = rem & 7;
    int lane = (rem >> 3) & 63;
    int blk = rem >> 9;
    int ncg = C >> 4;
    int kc = blk / ncg, cg = blk - kc * ncg;
    int k = kc * 32 + (lane >> 4) * 8 + j;
    int c = cg * 16 + (lane & 15);
    dst[idx] = f2b(W[(size_t)s * 128 * C + (size_t)k * C + c]);
}

// ---------------- CSR count via per-(graph,range) LDS histogram --------------

__global__ __launch_bounds__(1024)
void count_hist(const int* __restrict__ dst, int* __restrict__ cnt)
{
    __shared__ int hist[RANGE];
    const int g = blockIdx.y;
    const int r0 = blockIdx.x * RANGE;
    for (int i = threadIdx.x; i < RANGE; i += 1024) hist[i] = 0;
    __syncthreads();
    const int4* d4 = (const int4*)(dst + (size_t)g * EE);
    for (int i = threadIdx.x; i < EE / 4; i += 1024) {
        int4 v = d4[i];
        int a0 = v.x - r0; if ((unsigned)a0 < (unsigned)RANGE) atomicAdd(&hist[a0], 1);
        int a1 = v.y - r0; if ((unsigned)a1 < (unsigned)RANGE) atomicAdd(&hist[a1], 1);
        int a2 = v.z - r0; if ((unsigned)a2 < (unsigned)RANGE) atomicAdd(&hist[a2], 1);
        int a3 = v.w - r0; if ((unsigned)a3 < (unsigned)RANGE) atomicAdd(&hist[a3], 1);
    }
    __syncthreads();
    int* c = cnt + (size_t)g * NN;
    for (int i = threadIdx.x; i < RANGE; i += 1024) {
        int n = r0 + i;
        if (n < NN) c[n] = hist[i];
    }
}

__global__ __launch_bounds__(1024)
void scan_kernel(int* __restrict__ cnt, int* __restrict__ rows)
{
    int g = blockIdx.x;
    int tid = threadIdx.x;
    const int CH = (NN + 1023) / 1024;
    int s0 = tid * CH;
    int s1 = s0 + CH; if (s1 > NN) s1 = NN;
    int* c = cnt + (size_t)g * NN;
    int* ro = rows + (size_t)g * (NN + 1);
    int sum = 0;
    for (int i = s0; i < s1; ++i) sum += c[i];
    __shared__ int sd[1024];
    sd[tid] = sum;
    __syncthreads();
    for (int off = 1; off < 1024; off <<= 1) {
        int v = 0;
        if (tid >= off) v = sd[tid - off];
        __syncthreads();
        sd[tid] += v;
        __syncthreads();
    }
    int total = sd[1023];
    int prefix = (tid == 0) ? 0 : sd[tid - 1];
    for (int i = s0; i < s1; ++i) {
        int cv = c[i];
        ro[i] = prefix;
        c[i] = prefix;
        prefix += cv;
    }
    if (tid == 0) ro[NN] = total;
}

// ---------------- CSR fill: global atomic cursors, single dispatch (12 graphs)

__global__ __launch_bounds__(256)
void fill_kernel(const int* __restrict__ src, const int* __restrict__ dst,
                 const float* __restrict__ ew, int* __restrict__ cur,
                 int2* __restrict__ srcw)
{
    int g = blockIdx.y;
    int e = blockIdx.x * 256 + threadIdx.x;
    if (e >= EE) return;
    size_t idx = (size_t)g * EE + e;
    int d = dst[idx];
    int pos = atomicAdd(&cur[(size_t)g * NN + d], 1);
    int2 p;
    p.x = src[idx];
    p.y = __float_as_int(ew[idx]);
    srcw[(size_t)g * EE + pos] = p;
}

// ---------------- conv gather-aggregate, predicated 16-batch -----------------

__global__ __launch_bounds__(256)
void agg16_kernel(const unsigned short* __restrict__ x16,  // (N,128) bf16
                  const int2* __restrict__ srcw,           // (R,E)
                  const int* __restrict__ rows,            // (R,N+1)
                  unsigned short* __restrict__ agg16)      // (R,N,128) bf16
{
    int wid = (blockIdx.x * 256 + threadIdx.x) >> 6;
    int lane = threadIdx.x & 63;
    if (wid >= RR * NN) return;
    int r = wid / NN;
    int n = wid - r * NN;
    const int* rs = rows + (size_t)r * (NN + 1);
    int e0 = rs[n], e1 = rs[n + 1];
    const int2* sw = srcw + (size_t)r * EE;
    const int co = lane * 2;
    float ax = 0.f, ay = 0.f;
    for (int e = e0; e < e1; e += 16) {
        int2 p[16];
        unsigned int v[16];
#pragma unroll
        for (int i = 0; i < 16; ++i) {
            int idx = (e + i < e1) ? e + i : e1 - 1;
            p[i] = sw[idx];
        }
#pragma unroll
        for (int i = 0; i < 16; ++i)
            v[i] = *(const unsigned int*)(x16 + (size_t)p[i].x * 128 + co);
#pragma unroll
        for (int i = 0; i < 16; ++i) {
            float w = (e + i < e1) ? __int_as_float(p[i].y) : 0.f;
            ax += w * b2f((unsigned short)(v[i] & 0xffffu));
            ay += w * b2f((unsigned short)(v[i] >> 16));
        }
    }
    float inv = 1.0f / fmaxf((float)(e1 - e0), 1.0f);
    unsigned int o = (unsigned int)f2b(ax * inv) | ((unsigned int)f2b(ay * inv) << 16);
    *(unsigned int*)(agg16 + ((size_t)r * NN + n) * 128 + co) = o;
}

// ---------------- MFMA matmul: out = act(in @ W + b), K=128, 128 cols --------

__global__ __launch_bounds__(256)
void mmb(const void* in, int in_bf16, long in_zs, int ldin,
         const unsigned short* __restrict__ Ws, long w_zs,
         const float* __restrict__ bias, long b_zs,
         float* out, long out_zs, int ldout,
         unsigned short* out16, long out16_zs,
         int rows, int act)
{
    const int tid = threadIdx.x;
    const int wv = tid >> 6, l = tid & 63;
    const int z = blockIdx.z;
    const int r0 = blockIdx.x * 64 + wv * 16;
    const int lk = (l >> 4) * 8;
    int rowA = r0 + (l & 15);
    int rowc = rowA < rows ? rowA : rows - 1;

    bf16x8 a[4];
    if (in_bf16) {
        const unsigned short* inb = (const unsigned short*)in + (size_t)z * in_zs
                                    + (size_t)rowc * ldin + lk;
#pragma unroll
        for (int kc = 0; kc < 4; ++kc) {
            uint4 u = *(const uint4*)(inb + kc * 32);
            a[kc] = *(bf16x8*)&u;
        }
    } else {
        const float* inf = (const float*)in + (size_t)z * in_zs
                           + (size_t)rowc * ldin + lk;
#pragma unroll
        for (int kc = 0; kc < 4; ++kc) {
            float4 u0 = *(const float4*)(inf + kc * 32);
            float4 u1 = *(const float4*)(inf + kc * 32 + 4);
            a[kc] = pack8(u0, u1);
        }
    }

    const unsigned short* Wz = Ws + (size_t)z * w_zs;
    const float* bz = bias + (size_t)z * b_zs;
    float* oz = out ? out + (size_t)z * out_zs : (float*)0;
    unsigned short* o16z = out16 ? out16 + (size_t)z * out16_zs : (unsigned short*)0;
    const int colbase = l & 15;
    const int rbase = r0 + (l >> 4) * 4;

#pragma unroll
    for (int cg = 0; cg < 8; ++cg) {
        f32x4 acc = {0.f, 0.f, 0.f, 0.f};
#pragma unroll
        for (int kc = 0; kc < 4; ++kc) {
            uint4 bu = *(const uint4*)(Wz + ((size_t)(kc * 8 + cg) * 64 + l) * 8);
            acc = __builtin_amdgcn_mfma_f32_16x16x32_bf16(a[kc], *(bf16x8*)&bu, acc, 0, 0, 0);
        }
        int col = cg * 16 + colbase;
        float bvv = bz[col];
#pragma unroll
        for (int j = 0; j < 4; ++j) {
            int gr = rbase + j;
            if (gr >= rows) continue;
            float v = acc[j] + bvv;
            if (act) v = fmaxf(v, 0.f);
            if (oz) oz[(size_t)gr * ldout + col] = v;
            if (o16z) o16z[(size_t)gr * 128 + col] = f2b(v);
        }
    }
}

// ---------------- fused 4-timestep MFMA GRU: HS[t] <- outs_t (in-place) ------
// t-loop MUST stay rolled (#pragma unroll 1): full unroll quadruples live
// ranges -> 256 VGPR + scratch spill (round-12 regression, FETCH 719 MB).

__global__ __launch_bounds__(256)
void grub4(float* HS,                         // (T,N,128) fp32, in/out
           const unsigned short* __restrict__ Wis, const float* __restrict__ bi,
           const unsigned short* __restrict__ Whs, const float* __restrict__ bh)
{
    __shared__ __align__(16) unsigned short hbuf[4][16 * 136];
    const int tid = threadIdx.x;
    const int wv = tid >> 6, l = tid & 63;
    const int r0 = blockIdx.x * 64 + wv * 16;
    const int lo = l & 15, hi = l >> 4;
    const int lk = hi * 8;
    const int rowc = (r0 + lo) < NN ? (r0 + lo) : NN - 1;
    const int rbase = r0 + hi * 4;
    unsigned short* hb = hbuf[wv];

    for (int i = l; i < 16 * 136; i += 64) hb[i] = 0;

    float hold[8][4];
#pragma unroll
    for (int cg = 0; cg < 8; ++cg)
#pragma unroll
        for (int j = 0; j < 4; ++j) hold[cg][j] = 0.f;

#pragma unroll 1
    for (int t = 0; t < TT; ++t) {
        float* xt = HS + (size_t)t * NN * 128;
        bf16x8 ax[4], hx[4];
        const float* bx = xt + (size_t)rowc * 128 + lk;
#pragma unroll
        for (int kc = 0; kc < 4; ++kc) {
            ax[kc] = pack8(*(const float4*)(bx + kc * 32), *(const float4*)(bx + kc * 32 + 4));
            uint4 hu = *(const uint4*)(hb + lo * 136 + kc * 32 + lk);
            hx[kc] = *(bf16x8*)&hu;
        }

#pragma unroll 1
        for (int cg = 0; cg < 8; ++cg) {
            f32x4 air = {0.f,0.f,0.f,0.f}, ahr = {0.f,0.f,0.f,0.f};
            f32x4 aiz = {0.f,0.f,0.f,0.f}, ahz = {0.f,0.f,0.f,0.f};
            f32x4 ain = {0.f,0.f,0.f,0.f}, ahn = {0.f,0.f,0.f,0.f};
#pragma unroll
            for (int kc = 0; kc < 4; ++kc) {
                uint4 br = *(const uint4*)(Wis + ((size_t)(kc * 24 + 0 + cg) * 64 + l) * 8);
                uint4 hr = *(const uint4*)(Whs + ((size_t)(kc * 24 + 0 + cg) * 64 + l) * 8);
                uint4 bz = *(const uint4*)(Wis + ((size_t)(kc * 24 + 8 + cg) * 64 + l) * 8);
                uint4 hz = *(const uint4*)(Whs + ((size_t)(kc * 24 + 8 + cg) * 64 + l) * 8);
                uint4 bn = *(const uint4*)(Wis + ((size_t)(kc * 24 + 16 + cg) * 64 + l) * 8);
                uint4 hn = *(const uint4*)(Whs + ((size_t)(kc * 24 + 16 + cg) * 64 + l) * 8);
                air = __builtin_amdgcn_mfma_f32_16x16x32_bf16(ax[kc], *(bf16x8*)&br, air, 0, 0, 0);
                ahr = __builtin_amdgcn_mfma_f32_16x16x32_bf16(hx[kc], *(bf16x8*)&hr, ahr, 0, 0, 0);
                aiz = __builtin_amdgcn_mfma_f32_16x16x32_bf16(ax[kc], *(bf16x8*)&bz, aiz, 0, 0, 0);
                ahz = __builtin_amdgcn_mfma_f32_16x16x32_bf16(hx[kc], *(bf16x8*)&hz, ahz, 0, 0, 0);
                ain = __builtin_amdgcn_mfma_f32_16x16x32_bf16(ax[kc], *(bf16x8*)&bn, ain, 0, 0, 0);
                ahn = __builtin_amdgcn_mfma_f32_16x16x32_bf16(hx[kc], *(bf16x8*)&hn, ahn, 0, 0, 0);
            }
            int col = cg * 16 + lo;
            float bir = bi[col],       bhr = bh[col];
            float biz = bi[128 + col], bhz = bh[128 + col];
            float bin = bi[256 + col], bhn = bh[256 + col];
#pragma unroll
            for (int j = 0; j < 4; ++j) {
                float r_ = 1.f / (1.f + __expf(-(air[j] + bir + ahr[j] + bhr)));
                float z_ = 1.f / (1.f + __expf(-(aiz[j] + biz + ahz[j] + bhz)));
                float n_ = tanhf(ain[j] + bin + r_ * (ahn[j] + bhn));
                float o = (1.f - z_) * n_ + z_ * hold[cg][j];
                hold[cg][j] = o;
                int gr = rbase + j;
                if (gr < NN) xt[(size_t)gr * 128 + col] = o;   // outs_t (in-place)
                hb[(hi * 4 + j) * 136 + col] = f2b(o);          // h for next t (A-side)
            }
        }
    }
}

// ---------------- MFMA classifier: out = relu(Z @ cW1 + cb1) . cW2 + cb2 -----

__global__ __launch_bounds__(256)
void cls_mfma(const float* __restrict__ in,             // (N,384) fp32
              const unsigned short* __restrict__ Ws,    // swizzled cW1 (3 slices)
              const float* __restrict__ b1_,            // (128)
              const float* __restrict__ w2,             // (128)
              const float* __restrict__ b2_,            // (1)
              float* __restrict__ outv, int rows)
{
    const int tid = threadIdx.x;
    const int wv = tid >> 6, l = tid & 63;
    const int r0 = blockIdx.x * 64 + wv * 16;
    const int lk = (l >> 4) * 8;
    int rowA = r0 + (l & 15);
    int rowc = rowA < rows ? rowA : rows - 1;

    bf16x8 a[12];
    {
        const float* inf = in + (size_t)rowc * 384 + lk;
#pragma unroll
        for (int kc = 0; kc < 12; ++kc) {
            float4 u0 = *(const float4*)(inf + kc * 32);
            float4 u1 = *(const float4*)(inf + kc * 32 + 4);
            a[kc] = pack8(u0, u1);
        }
    }
    const int colbase = l & 15;
    const int rbase = r0 + (l >> 4) * 4;
    float part[4] = {0.f, 0.f, 0.f, 0.f};

#pragma unroll
    for (int cg = 0; cg < 8; ++cg) {
        f32x4 acc = {0.f, 0.f, 0.f, 0.f};
#pragma unroll
        for (int kc = 0; kc < 12; ++kc) {
            uint4 bu = *(const uint4*)(Ws + ((size_t)(kc * 8 + cg) * 64 + l) * 8);
            acc = __builtin_amdgcn_mfma_f32_16x16x32_bf16(a[kc], *(bf16x8*)&bu, acc, 0, 0, 0);
        }
        int col = cg * 16 + colbase;
        float b1v = b1_[col];
        float w2v = w2[col];
#pragma unroll
        for (int j = 0; j < 4; ++j)
            part[j] += fmaxf(acc[j] + b1v, 0.f) * w2v;
    }
    const float cb2v = b2_[0];
#pragma unroll
    for (int j = 0; j < 4; ++j) {
#pragma unroll
        for (int m = 1; m < 16; m <<= 1) part[j] += __shfl_xor(part[j], m);
        int gr = rbase + j;
        if ((l & 15) == 0 && gr < rows) outv[gr] = part[j] + cb2v;
    }
}

// ---------------- fused rel-attn + relu + residual + LayerNorm ----------------

__device__ inline float wred(float v)
{
#pragma unroll
    for (int m = 32; m; m >>= 1) v += __shfl_xor(v, m);
    return v;
}

__global__ __launch_bounds__(256)
void attnln_kernel(const unsigned short* __restrict__ agg16, // (R,N,128) bf16
                   const unsigned short* hin16,              // (N,128) bf16, may alias hout16
                   const float* __restrict__ q,
                   const float* __restrict__ g,
                   const float* __restrict__ b,
                   float* hout,                              // optional fp32
                   unsigned short* hout16)                   // optional bf16
{
    int wid = (blockIdx.x * 256 + threadIdx.x) >> 6;
    int lane = threadIdx.x & 63;
    if (wid >= NN) return;
    int n = wid;
    float2 qv = *(const float2*)(q + lane * 2);
    float sx[3], sy[3], sc[3];
#pragma unroll
    for (int r = 0; r < 3; ++r) {
        unsigned int v = *(const unsigned int*)(agg16 + ((size_t)r * NN + n) * 128 + lane * 2);
        sx[r] = b2f((unsigned short)(v & 0xffffu));
        sy[r] = b2f((unsigned short)(v >> 16));
        sc[r] = wred(tanhf(sx[r]) * qv.x + tanhf(sy[r]) * qv.y);
    }
    float mx = fmaxf(sc[0], fmaxf(sc[1], sc[2]));
    float e0 = __expf(sc[0] - mx), e1 = __expf(sc[1] - mx), e2 = __expf(sc[2] - mx);
    float isum = 1.f / (e0 + e1 + e2);
    float axv = (e0 * sx[0] + e1 * sx[1] + e2 * sx[2]) * isum;
    float ayv = (e0 * sy[0] + e1 * sy[1] + e2 * sy[2]) * isum;
    unsigned int hv = *(const unsigned int*)(hin16 + (size_t)n * 128 + lane * 2);
    float ux = b2f((unsigned short)(hv & 0xffffu)) + fmaxf(axv, 0.f);
    float uy = b2f((unsigned short)(hv >> 16)) + fmaxf(ayv, 0.f);
    float mean = wred(ux + uy) * (1.f / 128.f);
    float dx = ux - mean, dy = uy - mean;
    float var = wred(dx * dx + dy * dy) * (1.f / 128.f);
    float rstd = rsqrtf(var + 1e-5f);
    float2 gv = *(const float2*)(g + lane * 2);
    float2 bv = *(const float2*)(b + lane * 2);
    float ox = dx * rstd * gv.x + bv.x;
    float oy = dy * rstd * gv.y + bv.y;
    if (hout) {
        float2 o; o.x = ox; o.y = oy;
        *(float2*)(hout + (size_t)n * 128 + lane * 2) = o;
    }
    if (hout16) {
        unsigned int p = (unsigned int)f2b(ox) | ((unsigned int)f2b(oy) << 16);
        *(unsigned int*)(hout16 + (size_t)n * 128 + lane * 2) = p;
    }
}

// ---------------- temporal attention (also emits `last`) ----------------

__global__ __launch_bounds__(256)
void temporal_kernel(const float* __restrict__ outs, // (T,N,128)
                     const float* __restrict__ tq,
                     float* __restrict__ zbuf)       // (N,384)
{
    int wid = (blockIdx.x * 256 + threadIdx.x) >> 6;
    int lane = threadIdx.x & 63;
    if (wid >= NN) return;
    int n = wid;
    float2 qv = *(const float2*)(tq + lane * 2);
    float2 o[4];
    float sc[4];
#pragma unroll
    for (int t = 0; t < 4; ++t) {
        o[t] = *(const float2*)(outs + ((size_t)t * NN + n) * 128 + lane * 2);
        sc[t] = wred(tanhf(o[t].x) * qv.x + tanhf(o[t].y) * qv.y);
    }
    float mx = fmaxf(fmaxf(sc[0], sc[1]), fmaxf(sc[2], sc[3]));
    float e[4];
    float sum = 0.f;
#pragma unroll
    for (int t = 0; t < 4; ++t) { e[t] = __expf(sc[t] - mx); sum += e[t]; }
    float isum = 1.f / sum;
    float axv = 0.f, ayv = 0.f;
#pragma unroll
    for (int t = 0; t < 4; ++t) { axv += e[t] * o[t].x; ayv += e[t] * o[t].y; }
    axv *= isum; ayv *= isum;
    float* zr = zbuf + (size_t)n * 384;
    *(float2*)(zr + lane * 2) = o[3];
    float2 at; at.x = axv; at.y = ayv;
    *(float2*)(zr + 128 + lane * 2) = at;
}

// ---------------- launch ----------------

extern "C" void kernel_launch(void* const* d_in, const int* in_sizes, int n_in,
                              void* d_out, int out_size, void* d_ws, size_t ws_size,
                              hipStream_t stream)
{
    const float* feat = (const float*)d_in[0];
    const int* srcp   = (const int*)d_in[1];
    const int* dstp   = (const int*)d_in[2];
    const float* ewp  = (const float*)d_in[3];
    const float* W_in = (const float*)d_in[4];
    const float* b_in = (const float*)d_in[5];
    const float* W1   = (const float*)d_in[6];
    const float* b1   = (const float*)d_in[7];
    const float* W2   = (const float*)d_in[8];
    const float* b2   = (const float*)d_in[9];
    const float* q1   = (const float*)d_in[10];
    const float* q2   = (const float*)d_in[11];
    const float* ln1g = (const float*)d_in[12];
    const float* ln1b = (const float*)d_in[13];
    const float* ln2g = (const float*)d_in[14];
    const float* ln2b = (const float*)d_in[15];
    const float* gWih = (const float*)d_in[16];
    const float* gbih = (const float*)d_in[17];
    const float* gWhh = (const float*)d_in[18];
    const float* gbhh = (const float*)d_in[19];
    const float* tq   = (const float*)d_in[20];
    const float* tW1  = (const float*)d_in[21];
    const float* tb1  = (const float*)d_in[22];
    const float* tW2  = (const float*)d_in[23];
    const float* tb2  = (const float*)d_in[24];
    const float* cW1  = (const float*)d_in[25];
    const float* cb1  = (const float*)d_in[26];
    const float* cW2  = (const float*)d_in[27];
    const float* cb2  = (const float*)d_in[28];
    float* outv = (float*)d_out;
    (void)in_sizes; (void)n_in; (void)out_size;

    // ---- ws layout (bytes), peak ~207.0 MB (<=218 proven) ----
    const size_t o_HS    = 0;                          // (T,N,128) fp32 = 102,400,000
    const size_t o_POOL  = 102400000;
    const size_t o_AGG16 = o_POOL;                     // (R,N,128) bf16 = 38,400,000
    const size_t o_H16   = o_POOL + 38400000;          // (N,128) bf16 = 12,800,000
    const size_t o_SRCW  = o_POOL + 51200000;          // (12,E) int2 = 48,000,000
    const size_t o_ROWS  = o_POOL + 99200000;          // (12,N+1) int -> pad
    const size_t o_CURS  = o_POOL + 101600128;         // (12,N) int
    const size_t o_ZB    = o_POOL;                     // phase C: (N,384) fp32
    const size_t o_TAB   = o_POOL + 76800000;          // phase C: (N,128) bf16
    const size_t o_WSZ   = o_POOL + 104000128;         // swizzled bf16 weights
    const size_t NEED    = o_WSZ + 589824;

    if (ws_size < NEED) {
        diag_kernel<<<dim3((NN + 255) / 256), dim3(256), 0, stream>>>(outv, (float)(ws_size >> 20));
        return;
    }

    char* wsb = (char*)d_ws;
    float* HS             = (float*)(wsb + o_HS);
    unsigned short* AGG16 = (unsigned short*)(wsb + o_AGG16);
    unsigned short* H16   = (unsigned short*)(wsb + o_H16);
    int2*  SRCW           = (int2*)(wsb + o_SRCW);
    int*   ROWS           = (int*)(wsb + o_ROWS);
    int*   CURS           = (int*)(wsb + o_CURS);
    float* ZB             = (float*)(wsb + o_ZB);
    unsigned short* TAB16 = (unsigned short*)(wsb + o_TAB);
    unsigned short* WSZ   = (unsigned short*)(wsb + o_WSZ);

    unsigned short* Wins  = WSZ;            // 16384
    unsigned short* W1s   = WSZ + 16384;    // 49152
    unsigned short* W2s   = WSZ + 65536;    // 49152
    unsigned short* gWihs = WSZ + 114688;   // 49152
    unsigned short* gWhhs = WSZ + 163840;   // 49152
    unsigned short* tW1s  = WSZ + 212992;   // 16384
    unsigned short* tW2s  = WSZ + 229376;   // 16384
    unsigned short* cW1s  = WSZ + 245760;   // 49152

    const dim3 blk(256);
    const int G64 = (NN + 63) / 64;

    // ---------- weight swizzle ----------
    wswz_kernel<<<dim3((1 * 16384 + 255) / 256), blk, 0, stream>>>(W_in, Wins, 128, 1);
    wswz_kernel<<<dim3((3 * 16384 + 255) / 256), blk, 0, stream>>>(W1,   W1s,  128, 3);
    wswz_kernel<<<dim3((3 * 16384 + 255) / 256), blk, 0, stream>>>(W2,   W2s,  128, 3);
    wswz_kernel<<<dim3((1 * 49152 + 255) / 256), blk, 0, stream>>>(gWih, gWihs, 384, 1);
    wswz_kernel<<<dim3((1 * 49152 + 255) / 256), blk, 0, stream>>>(gWhh, gWhhs, 384, 1);
    wswz_kernel<<<dim3((1 * 16384 + 255) / 256), blk, 0, stream>>>(tW1,  tW1s, 128, 1);
    wswz_kernel<<<dim3((1 * 16384 + 255) / 256), blk, 0, stream>>>(tW2,  tW2s, 128, 1);
    wswz_kernel<<<dim3((3 * 16384 + 255) / 256), blk, 0, stream>>>(cW1,  cW1s, 128, 3);

    // ---------- CSR: count (LDS hist) + scan + fill (global cursors, 1 dispatch) ----------
    count_hist<<<dim3(NRANGE, TT * RR), dim3(1024), 0, stream>>>(dstp, CURS);
    scan_kernel<<<dim3(TT * RR), dim3(1024), 0, stream>>>(CURS, ROWS);
    fill_kernel<<<dim3((EE + 255) / 256, TT * RR), blk, 0, stream>>>(srcp, dstp, ewp, CURS, SRCW);

    // ---------- phase A: spatial layers, t-outer ----------
    for (int t = 0; t < TT; ++t) {
        // h0 = relu(feat[t] @ W_in + b_in) -> H16 (bf16 only)
        mmb<<<dim3(G64, 1, 1), blk, 0, stream>>>(
            (const void*)(feat + (size_t)t * NN * 128), 0, 0, 128,
            Wins, 0, b_in, 0, (float*)0, 0, 0, H16, 0, NN, 1);

        for (int layer = 0; layer < 2; ++layer) {
            const unsigned short* Wls = layer ? W2s : W1s;
            const float* bl = layer ? b2 : b1;
            const float* ql = layer ? q2 : q1;
            const float* lg = layer ? ln2g : ln1g;
            const float* lb = layer ? ln2b : ln1b;
            float* hout = layer ? (HS + (size_t)t * NN * 128) : (float*)0;
            unsigned short* hout16 = layer ? (unsigned short*)0 : H16;

            agg16_kernel<<<dim3((RR * NN) / 4), blk, 0, stream>>>(
                H16, SRCW + (size_t)t * RR * EE, ROWS + (size_t)t * RR * (NN + 1), AGG16);
            mmb<<<dim3(G64, 1, RR), blk, 0, stream>>>(
                (const void*)AGG16, 1, (long)NN * 128, 128,
                Wls, 16384, bl, 128, (float*)0, 0, 0, AGG16, (long)NN * 128, NN, 0);
            attnln_kernel<<<dim3(NN / 4), blk, 0, stream>>>(
                AGG16, H16, ql, lg, lb, hout, hout16);
        }
    }

    // ---------- phase B: fully-fused 4-step GRU (in-place on HS) ----------
    grub4<<<dim3(G64), blk, 0, stream>>>(HS, gWihs, gbih, gWhhs, gbhh);

    // ---------- phase C: temporal attn + tab + classifier ----------
    temporal_kernel<<<dim3(NN / 4), blk, 0, stream>>>(HS, tq, ZB);

    mmb<<<dim3(G64, 1, 1), blk, 0, stream>>>(
        (const void*)(feat + (size_t)3 * NN * 128), 0, 0, 128,
        tW1s, 0, tb1, 0, (float*)0, 0, 0, TAB16, 0, NN, 1);
    mmb<<<dim3(G64, 1, 1), blk, 0, stream>>>(
        (const void*)TAB16, 1, 0, 128,
        tW2s, 0, tb2, 0, ZB + 256, 0, 384, (unsigned short*)0, 0, NN, 1);

    cls_mfma<<<dim3(G64), blk, 0, stream>>>(ZB, cW1s, cb1, cW2, cb2, outv, NN);
}